// Round 13
// baseline (52.488 us; speedup 1.0000x reference)
//
#include <hip/hip_runtime.h>
#include <hip/hip_bf16.h>

// B=128, C=32, K=128
// out[b,c,i,j] = s[b,c],  s[b,c] = sum_k (u[c,k]+b_row[c]) * (v[c,k]+b_col[c])
//   u[c,k] = sum_i w_row[c,i] * X[b,i,k]   (column read -> row-slice per i)
//   v[c,k] = sum_j w_col[c,j] * X[b,k,j]   (ROW read of row k -> no X^T tile!)
//
// FUSED v5: single swizzled X tile + global_load_lds staging.
//  - ONE 64 KB tile; chunk swizzle chunk' = chunk ^ ((row>>2)&31):
//      u-read: row-uniform, XOR const -> lane permutation, CF
//      v-read: lanes read rows 4kq+r (row>>2 = kq distinct/lane) -> distinct
//        chunks; each 8-lane group spans 8 distinct chunk&7 -> CF
//      staging: linear chunks across lanes -> CF
//  - staging via __builtin_amdgcn_global_load_lds width=16, LINEAR LDS dest,
//    per-lane PRE-SWIZZLED global source (m201 pattern; swizzle both-sides)
//    -> no VGPR round trip, no ds_writes, no transpose VALU (R12's prefix cost)
//  - role-split compute kept from R12 (waves 0-3: u, 4-7: v, 4 c's each)
// Retained: non-redundant fusion (R10), XCD-paired bids, plain stores (R3),
// LDS-weights not s_load (R7), f32 throughout (R11).

constexpr int KDIM = 128;
constexpr int CDIM = 32;

// grid = 256: xcd = bid&7, idx = bid>>3; b = xcd*16 + (idx>>1), ch = idx&1
__global__ __launch_bounds__(512) void fused_kernel(
    const float* __restrict__ x,
    const float* __restrict__ w_col, const float* __restrict__ b_col,
    const float* __restrict__ w_row, const float* __restrict__ b_row,
    float* __restrict__ out)
{
    __shared__ __align__(16) float xs[KDIM * KDIM];  // 64 KB swizzled tile; later exchange
    __shared__ float4 wu4[KDIM][4];   // wu4[i][g] = w_row[C0+4g+0..3][i]     (8 KB)
    __shared__ float4 wcv[16][32];    // wcv[c][jc] = w_col[C0+c][4jc..4jc+3] (8 KB)
    __shared__ float  s_b[16];

    const int bid  = blockIdx.x;
    const int xcd  = bid & 7;
    const int idx  = bid >> 3;               // 0..31
    const int b    = xcd * 16 + (idx >> 1);  // ch-pair of a b shares an XCD
    const int ch   = idx & 1;
    const int C0   = ch * 16;
    const int tid  = threadIdx.x;
    const int w    = tid >> 6;               // wave 0..7
    const int lane = tid & 63;

    // ---- async X staging: linear LDS dest, pre-swizzled per-lane source ----
    const float* xg = x + (size_t)b * KDIM * KDIM;
    {
        const int cb = w * 64 + lane;            // wave-linear chunk ids
        #pragma unroll
        for (int e = 0; e < 8; ++e) {
            const int c    = cb + 512 * e;       // LDS chunk 0..4095
            const int row  = c >> 5;             // 32 chunks per 128-f32 row
            const int scol = (c & 31) ^ ((c >> 7) & 31);   // source chunk (involution)
            __builtin_amdgcn_global_load_lds(
                (const __attribute__((address_space(1))) unsigned int*)(xg + row * KDIM + 4 * scol),
                (__attribute__((address_space(3))) unsigned int*)(&xs[4 * c]),
                16, 0, 0);
        }
    }
    // ---- weights: one wu4 entry + one wcv entry per thread (overlap with async) ----
    {
        const int i = tid & 127;
        const int g = tid >> 7;              // 0..3
        wu4[i][g] = make_float4(w_row[(C0 + 4 * g + 0) * KDIM + i],
                                w_row[(C0 + 4 * g + 1) * KDIM + i],
                                w_row[(C0 + 4 * g + 2) * KDIM + i],
                                w_row[(C0 + 4 * g + 3) * KDIM + i]);
        const int c16 = tid >> 5;            // 0..15
        const int jc  = tid & 31;            // 0..31
        wcv[c16][jc] = *reinterpret_cast<const float4*>(&w_col[(C0 + c16) * KDIM + 4 * jc]);
    }
    __syncthreads();   // B1: drains vmcnt -> tile + weights ready

    // ---- compute: role = w>>2 (0:u, 1:v); g = w&3 -> c-quad C0+4g..+3 ----
    const int role = w >> 2;
    const int g    = w & 3;
    const int kq   = lane & 31;    // 4-k chunk -> k = 4kq..4kq+3
    const int ih   = lane >> 5;    // reduction half

    float a[4][4] = {{0,0,0,0},{0,0,0,0},{0,0,0,0},{0,0,0,0}};   // [cc][k-offset]

    if (role == 0) {
        // u[c,k] = sum_i wr[c][i] * X[i][k]: row-slice reads, i over ih-half
        #pragma unroll 4
        for (int ii = 0; ii < 64; ++ii) {
            const int i     = ih * 64 + ii;
            const int chunk = kq ^ ((i >> 2) & 31);
            const float4 xv = *reinterpret_cast<const float4*>(&xs[i * KDIM + 4 * chunk]);
            const float4 wq = wu4[i][g];     // broadcast
            #pragma unroll
            for (int cc = 0; cc < 4; ++cc) {
                const float ww = (&wq.x)[cc];
                a[cc][0] = fmaf(ww, xv.x, a[cc][0]);
                a[cc][1] = fmaf(ww, xv.y, a[cc][1]);
                a[cc][2] = fmaf(ww, xv.z, a[cc][2]);
                a[cc][3] = fmaf(ww, xv.w, a[cc][3]);
            }
        }
    } else {
        // v[c,k] = sum_j wc[c][j] * X[k][j]: lane reads its 4 rows 4kq+r, j over ih-half
        #pragma unroll 2
        for (int jj = 0; jj < 16; ++jj) {
            const int jcol = ih * 16 + jj;           // j-chunk
            float4 tv[4];
            #pragma unroll
            for (int r = 0; r < 4; ++r) {
                const int row   = 4 * kq + r;        // row>>2 == kq
                const int chunk = jcol ^ kq;
                tv[r] = *reinterpret_cast<const float4*>(&xs[row * KDIM + 4 * chunk]);
            }
            #pragma unroll
            for (int cc = 0; cc < 4; ++cc) {
                const float4 wq = wcv[4 * g + cc][jcol];   // broadcast
                #pragma unroll
                for (int r = 0; r < 4; ++r) {
                    a[cc][r] = fmaf(wq.x, tv[r].x, a[cc][r]);
                    a[cc][r] = fmaf(wq.y, tv[r].y, a[cc][r]);
                    a[cc][r] = fmaf(wq.z, tv[r].z, a[cc][r]);
                    a[cc][r] = fmaf(wq.w, tv[r].w, a[cc][r]);
                }
            }
        }
    }

    // ---- combine reduction halves (lane ^ 32) ----
    #pragma unroll
    for (int cc = 0; cc < 4; ++cc)
        #pragma unroll
        for (int q = 0; q < 4; ++q)
            a[cc][q] += __shfl_xor(a[cc][q], 32);

    __syncthreads();   // B2: all tile reads done -> xs reusable as exchange

    // ---- exchange into dead xs: u at [0..2047], v at [2048..4095], c-major ----
    if (lane < 32) {
        float* ex = xs + role * 2048;
        #pragma unroll
        for (int cc = 0; cc < 4; ++cc) {
            *reinterpret_cast<float4*>(&ex[(4 * g + cc) * KDIM + 4 * kq]) =
                make_float4(a[cc][0], a[cc][1], a[cc][2], a[cc][3]);
        }
    }
    __syncthreads();   // B3

    // ---- dot pass: 32-lane group cg -> s[C0+cg] ----
    {
        const int cg  = tid >> 5;            // 0..15
        const int kq2 = tid & 31;
        const float4 uu = *reinterpret_cast<const float4*>(&xs[cg * KDIM + 4 * kq2]);
        const float4 vv = *reinterpret_cast<const float4*>(&xs[2048 + cg * KDIM + 4 * kq2]);
        const int c = C0 + cg;
        const float br = b_row[c];
        const float bc = b_col[c];
        float p = (uu.x + br) * (vv.x + bc) + (uu.y + br) * (vv.y + bc)
                + (uu.z + br) * (vv.z + bc) + (uu.w + br) * (vv.w + bc);
        #pragma unroll
        for (int off = 1; off < 32; off <<= 1) p += __shfl_xor(p, off, 32);
        if (kq2 == 0) s_b[cg] = p;
    }
    __syncthreads();   // B4

    // ---- write phase: 16 slabs (1 MB), block-wide coalesced float4 ----
    float4* out4 = reinterpret_cast<float4*>(out);
    #pragma unroll
    for (int cl = 0; cl < 16; ++cl) {
        const float val = s_b[cl];           // LDS broadcast
        float4 v4;
        v4.x = v4.y = v4.z = v4.w = val;
        float4* o = out4 + (size_t)(b * CDIM + C0 + cl) * 4096;
        #pragma unroll
        for (int r = 0; r < 8; ++r) {
            o[tid + 512 * r] = v4;
        }
    }
}

extern "C" void kernel_launch(void* const* d_in, const int* in_sizes, int n_in,
                              void* d_out, int out_size, void* d_ws, size_t ws_size,
                              hipStream_t stream) {
    const float* x     = (const float*)d_in[0];
    const float* w_col = (const float*)d_in[1];
    const float* b_col = (const float*)d_in[2];
    const float* w_row = (const float*)d_in[3];
    const float* b_row = (const float*)d_in[4];
    float* out = (float*)d_out;

    fused_kernel<<<256, 512, 0, stream>>>(x, w_col, b_col, w_row, b_row, out);
}

// Round 14
// 50.962 us; speedup vs baseline: 1.0299x; 1.0299x over previous
//
#include <hip/hip_runtime.h>
#include <hip/hip_bf16.h>

// B=128, C=32, K=128
// out[b,c,i,j] = s[b,c],  s[b,c] = sum_k (u[c,k]+b_row[c]) * (v[c,k]+b_col[c])
//   u[c,k] = sum_i w_row[c,i] * X[b,i,k]   (column read -> row-slice per i)
//   v[c,k] = sum_j w_col[c,j] * X[b,k,j]   (ROW read of row k -> no X^T tile)
//
// FUSED v6 = R13 with the serial tail trimmed:
//  - exchange goes to a SEPARATE 16 KB buffer (uvx), not into dead xs
//    -> no WAR on the tile -> B2 barrier removed
//  - per-group immediate write: each 32-lane dot group holds s uniform and
//    streams its own 64 KB slab -> s_b broadcast + B4 removed
//  - barriers 4 -> 2 (post-stage, post-exchange)
// Everything else identical to R13 (52.5 us):
//  - single 64 KB tile, chunk swizzle chunk' = chunk ^ ((row>>2)&31)
//  - global_load_lds width=16, linear LDS dest, pre-swizzled source
//  - role-split compute (waves 0-3 u, 4-7 v), XCD-paired bids, plain stores.

constexpr int KDIM = 128;
constexpr int CDIM = 32;

// grid = 256: xcd = bid&7, idx = bid>>3; b = xcd*16 + (idx>>1), ch = idx&1
__global__ __launch_bounds__(512) void fused_kernel(
    const float* __restrict__ x,
    const float* __restrict__ w_col, const float* __restrict__ b_col,
    const float* __restrict__ w_row, const float* __restrict__ b_row,
    float* __restrict__ out)
{
    __shared__ __align__(16) float xs[KDIM * KDIM];   // 64 KB swizzled tile
    __shared__ float4 wu4[KDIM][4];    // wu4[i][g] = w_row[C0+4g+0..3][i]     (8 KB)
    __shared__ float4 wcv[16][32];     // wcv[c][jc] = w_col[C0+c][4jc..4jc+3] (8 KB)
    __shared__ __align__(16) float uvx[2 * 16 * KDIM]; // u/v exchange (16 KB)

    const int bid  = blockIdx.x;
    const int xcd  = bid & 7;
    const int idx  = bid >> 3;               // 0..31
    const int b    = xcd * 16 + (idx >> 1);  // ch-pair of a b shares an XCD
    const int ch   = idx & 1;
    const int C0   = ch * 16;
    const int tid  = threadIdx.x;
    const int w    = tid >> 6;               // wave 0..7
    const int lane = tid & 63;

    // ---- async X staging: linear LDS dest, pre-swizzled per-lane source ----
    const float* xg = x + (size_t)b * KDIM * KDIM;
    {
        const int cb = w * 64 + lane;            // wave-linear chunk ids
        #pragma unroll
        for (int e = 0; e < 8; ++e) {
            const int c    = cb + 512 * e;       // LDS chunk 0..4095
            const int row  = c >> 5;             // 32 chunks per 128-f32 row
            const int scol = (c & 31) ^ ((c >> 7) & 31);   // source chunk (involution)
            __builtin_amdgcn_global_load_lds(
                (const __attribute__((address_space(1))) unsigned int*)(xg + row * KDIM + 4 * scol),
                (__attribute__((address_space(3))) unsigned int*)(&xs[4 * c]),
                16, 0, 0);
        }
    }
    // ---- weights: one wu4 entry + one wcv entry per thread (overlap with async) ----
    {
        const int i = tid & 127;
        const int g = tid >> 7;              // 0..3
        wu4[i][g] = make_float4(w_row[(C0 + 4 * g + 0) * KDIM + i],
                                w_row[(C0 + 4 * g + 1) * KDIM + i],
                                w_row[(C0 + 4 * g + 2) * KDIM + i],
                                w_row[(C0 + 4 * g + 3) * KDIM + i]);
        const int c16 = tid >> 5;            // 0..15
        const int jc  = tid & 31;            // 0..31
        wcv[c16][jc] = *reinterpret_cast<const float4*>(&w_col[(C0 + c16) * KDIM + 4 * jc]);
    }
    __syncthreads();   // B1: drains vmcnt -> tile + weights ready

    // ---- compute: role = w>>2 (0:u, 1:v); g = w&3 -> c-quad C0+4g..+3 ----
    const int role = w >> 2;
    const int g    = w & 3;
    const int kq   = lane & 31;    // 4-k chunk -> k = 4kq..4kq+3
    const int ih   = lane >> 5;    // reduction half

    float a[4][4] = {{0,0,0,0},{0,0,0,0},{0,0,0,0},{0,0,0,0}};   // [cc][k-offset]

    if (role == 0) {
        // u[c,k] = sum_i wr[c][i] * X[i][k]: row-slice reads, i over ih-half
        #pragma unroll 4
        for (int ii = 0; ii < 64; ++ii) {
            const int i     = ih * 64 + ii;
            const int chunk = kq ^ ((i >> 2) & 31);
            const float4 xv = *reinterpret_cast<const float4*>(&xs[i * KDIM + 4 * chunk]);
            const float4 wq = wu4[i][g];     // broadcast
            #pragma unroll
            for (int cc = 0; cc < 4; ++cc) {
                const float ww = (&wq.x)[cc];
                a[cc][0] = fmaf(ww, xv.x, a[cc][0]);
                a[cc][1] = fmaf(ww, xv.y, a[cc][1]);
                a[cc][2] = fmaf(ww, xv.z, a[cc][2]);
                a[cc][3] = fmaf(ww, xv.w, a[cc][3]);
            }
        }
    } else {
        // v[c,k] = sum_j wc[c][j] * X[k][j]: lane reads its 4 rows 4kq+r, j over ih-half
        #pragma unroll 2
        for (int jj = 0; jj < 16; ++jj) {
            const int jcol = ih * 16 + jj;           // j-chunk
            float4 tv[4];
            #pragma unroll
            for (int r = 0; r < 4; ++r) {
                const int row   = 4 * kq + r;        // row>>2 == kq
                const int chunk = jcol ^ kq;
                tv[r] = *reinterpret_cast<const float4*>(&xs[row * KDIM + 4 * chunk]);
            }
            #pragma unroll
            for (int cc = 0; cc < 4; ++cc) {
                const float4 wq = wcv[4 * g + cc][jcol];   // broadcast
                #pragma unroll
                for (int r = 0; r < 4; ++r) {
                    a[cc][r] = fmaf(wq.x, tv[r].x, a[cc][r]);
                    a[cc][r] = fmaf(wq.y, tv[r].y, a[cc][r]);
                    a[cc][r] = fmaf(wq.z, tv[r].z, a[cc][r]);
                    a[cc][r] = fmaf(wq.w, tv[r].w, a[cc][r]);
                }
            }
        }
    }

    // ---- combine reduction halves (lane ^ 32) ----
    #pragma unroll
    for (int cc = 0; cc < 4; ++cc)
        #pragma unroll
        for (int q = 0; q < 4; ++q)
            a[cc][q] += __shfl_xor(a[cc][q], 32);

    // ---- exchange into uvx: u at [0..2047], v at [2048..4095], c-major ----
    // (separate buffer -> no WAR on xs -> no pre-exchange barrier needed)
    if (lane < 32) {
        float* ex = uvx + role * 2048;
        #pragma unroll
        for (int cc = 0; cc < 4; ++cc) {
            *reinterpret_cast<float4*>(&ex[(4 * g + cc) * KDIM + 4 * kq]) =
                make_float4(a[cc][0], a[cc][1], a[cc][2], a[cc][3]);
        }
    }
    __syncthreads();   // B2: exchange visible

    // ---- dot pass: 32-lane group cg -> s[C0+cg], then IMMEDIATE slab write ----
    {
        const int cg  = tid >> 5;            // 0..15
        const int kq2 = tid & 31;
        const float4 uu = *reinterpret_cast<const float4*>(&uvx[cg * KDIM + 4 * kq2]);
        const float4 vv = *reinterpret_cast<const float4*>(&uvx[2048 + cg * KDIM + 4 * kq2]);
        const int c = C0 + cg;
        const float br = b_row[c];
        const float bc = b_col[c];
        float p = (uu.x + br) * (vv.x + bc) + (uu.y + br) * (vv.y + bc)
                + (uu.z + br) * (vv.z + bc) + (uu.w + br) * (vv.w + bc);
        #pragma unroll
        for (int off = 1; off < 32; off <<= 1) p += __shfl_xor(p, off, 32);
        // p uniform in the 32-lane group -> stream slab (C0+cg) directly
        float4 v4;
        v4.x = v4.y = v4.z = v4.w = p;
        float4* o = reinterpret_cast<float4*>(out) + (size_t)(b * CDIM + c) * 4096;
        #pragma unroll 8
        for (int r = 0; r < 128; ++r) {
            o[kq2 + 32 * r] = v4;
        }
    }
}

extern "C" void kernel_launch(void* const* d_in, const int* in_sizes, int n_in,
                              void* d_out, int out_size, void* d_ws, size_t ws_size,
                              hipStream_t stream) {
    const float* x     = (const float*)d_in[0];
    const float* w_col = (const float*)d_in[1];
    const float* b_col = (const float*)d_in[2];
    const float* w_row = (const float*)d_in[3];
    const float* b_row = (const float*)d_in[4];
    float* out = (float*)d_out;

    fused_kernel<<<256, 512, 0, stream>>>(x, w_col, b_col, w_row, b_row, out);
}

// Round 15
// 49.777 us; speedup vs baseline: 1.0545x; 1.0238x over previous
//
#include <hip/hip_runtime.h>
#include <hip/hip_bf16.h>

// B=128, C=32, K=128
// out[b,c,i,j] = s[b,c],  s[b,c] = sum_k (u[c,k]+b_row[c]) * (v[c,k]+b_col[c])
//   u[c,k] = sum_i w_row[c,i] * X[b,i,k]
//   v[c,k] = sum_j w_col[c,j] * X[b,k,j]   (row read of row k -> no X^T tile)
//
// FUSED v7: 2 blocks/CU for cross-block prefix/write overlap.
//  R14 was 1 block/CU (96 KB LDS): every CU serialized (prefix ~5us -> write).
//  Now each block owns 8 c's (grid 512), LDS = 64(xs) + 4(wu2) + 4(wcv)
//  + 8(uvx) = EXACTLY 80 KB -> 2 blocks/CU: one block's write stream hides
//  the other's staging+compute.
//  - single 64 KB tile, chunk swizzle chunk' = chunk ^ ((row>>2)&31) (R13)
//  - global_load_lds width=16, linear LDS dest, pre-swizzled source (R13)
//  - role-split: waves 0-3 u (2 c's each), waves 4-7 v (2 c's each)
//  - dot: one wave per c, 64-lane butterfly -> wave streams its own 64 KB
//    slab (1 KB/instr full-wave coalesced)
//  - 2 barriers only (post-stage, post-exchange) (R14)
// Retained: XCD-paired bids, plain stores (R3), LDS weights (R7), f32 (R11).

constexpr int KDIM = 128;
constexpr int CDIM = 32;

// grid = 512: xcd = bid&7, idx = bid>>3 (0..63); b = xcd*16 + (idx>>2), oct = idx&3
__global__ __launch_bounds__(512, 4) void fused_kernel(
    const float* __restrict__ x,
    const float* __restrict__ w_col, const float* __restrict__ b_col,
    const float* __restrict__ w_row, const float* __restrict__ b_row,
    float* __restrict__ out)
{
    __shared__ __align__(16) float xs[KDIM * KDIM];    // 64 KB swizzled tile
    __shared__ float2 wu2[KDIM][4];    // wu2[i][g] = (w_row[C0+2g][i], w_row[C0+2g+1][i]) (4 KB)
    __shared__ float4 wcv[8][32];      // wcv[c][jc] = w_col[C0+c][4jc..4jc+3]             (4 KB)
    __shared__ __align__(16) float uvx[2 * 8 * KDIM];  // u/v exchange (8 KB)

    const int bid  = blockIdx.x;
    const int xcd  = bid & 7;
    const int idx  = bid >> 3;               // 0..63
    const int b    = xcd * 16 + (idx >> 2);  // 4 octet-blocks of a b share an XCD
    const int oct  = idx & 3;
    const int C0   = oct * 8;
    const int tid  = threadIdx.x;
    const int w    = tid >> 6;               // wave 0..7
    const int lane = tid & 63;

    // ---- async X staging: linear LDS dest, pre-swizzled per-lane source ----
    const float* xg = x + (size_t)b * KDIM * KDIM;
    {
        const int cb = w * 64 + lane;            // wave-linear chunk ids
        #pragma unroll
        for (int e = 0; e < 8; ++e) {
            const int c    = cb + 512 * e;       // LDS chunk 0..4095
            const int row  = c >> 5;             // 32 chunks per 128-f32 row
            const int scol = (c & 31) ^ ((c >> 7) & 31);   // source chunk (involution)
            __builtin_amdgcn_global_load_lds(
                (const __attribute__((address_space(1))) unsigned int*)(xg + row * KDIM + 4 * scol),
                (__attribute__((address_space(3))) unsigned int*)(&xs[4 * c]),
                16, 0, 0);
        }
    }
    // ---- weights (overlap with async staging) ----
    if (tid < 256) {
        const int i = tid & 127;
        const int g = (tid >> 7) * 2;        // 0 or 2 -> covers g=0..3 via two c each
        wu2[i][g]     = make_float2(w_row[(C0 + 2 * g + 0) * KDIM + i],
                                    w_row[(C0 + 2 * g + 1) * KDIM + i]);
        wu2[i][g + 1] = make_float2(w_row[(C0 + 2 * g + 2) * KDIM + i],
                                    w_row[(C0 + 2 * g + 3) * KDIM + i]);
    } else {
        const int t  = tid - 256;            // 0..255
        const int c8 = t >> 5;               // 0..7
        const int jc = t & 31;               // 0..31
        wcv[c8][jc] = *reinterpret_cast<const float4*>(&w_col[(C0 + c8) * KDIM + 4 * jc]);
    }
    __syncthreads();   // B1: drains vmcnt -> tile + weights ready

    // ---- compute: role = w>>2 (0:u, 1:v); g = w&3 -> c-pair C0+2g, C0+2g+1 ----
    const int role = w >> 2;
    const int g    = w & 3;
    const int kq   = lane & 31;    // 4-k chunk -> k = 4kq..4kq+3
    const int ih   = lane >> 5;    // reduction half

    float a[2][4] = {{0,0,0,0},{0,0,0,0}};   // [cc][k-offset]

    if (role == 0) {
        // u[c,k] = sum_i wr[c][i] * X[i][k]: row-slice reads, i over ih-half
        #pragma unroll 4
        for (int ii = 0; ii < 64; ++ii) {
            const int i     = ih * 64 + ii;
            const int chunk = kq ^ ((i >> 2) & 31);
            const float4 xv = *reinterpret_cast<const float4*>(&xs[i * KDIM + 4 * chunk]);
            const float2 wq = wu2[i][g];     // broadcast
            a[0][0] = fmaf(wq.x, xv.x, a[0][0]); a[0][1] = fmaf(wq.x, xv.y, a[0][1]);
            a[0][2] = fmaf(wq.x, xv.z, a[0][2]); a[0][3] = fmaf(wq.x, xv.w, a[0][3]);
            a[1][0] = fmaf(wq.y, xv.x, a[1][0]); a[1][1] = fmaf(wq.y, xv.y, a[1][1]);
            a[1][2] = fmaf(wq.y, xv.z, a[1][2]); a[1][3] = fmaf(wq.y, xv.w, a[1][3]);
        }
    } else {
        // v[c,k] = sum_j wc[c][j] * X[k][j]: lane reads its 4 rows 4kq+r, j over ih-half
        #pragma unroll 2
        for (int jj = 0; jj < 16; ++jj) {
            const int jcol = ih * 16 + jj;           // j-chunk
            float4 tv[4];
            #pragma unroll
            for (int r = 0; r < 4; ++r) {
                const int row   = 4 * kq + r;        // row>>2 == kq
                const int chunk = jcol ^ kq;
                tv[r] = *reinterpret_cast<const float4*>(&xs[row * KDIM + 4 * chunk]);
            }
            #pragma unroll
            for (int cc = 0; cc < 2; ++cc) {
                const float4 wq = wcv[2 * g + cc][jcol];   // broadcast
                #pragma unroll
                for (int r = 0; r < 4; ++r) {
                    a[cc][r] = fmaf(wq.x, tv[r].x, a[cc][r]);
                    a[cc][r] = fmaf(wq.y, tv[r].y, a[cc][r]);
                    a[cc][r] = fmaf(wq.z, tv[r].z, a[cc][r]);
                    a[cc][r] = fmaf(wq.w, tv[r].w, a[cc][r]);
                }
            }
        }
    }

    // ---- combine reduction halves (lane ^ 32) ----
    #pragma unroll
    for (int cc = 0; cc < 2; ++cc)
        #pragma unroll
        for (int q = 0; q < 4; ++q)
            a[cc][q] += __shfl_xor(a[cc][q], 32);

    // ---- exchange into uvx: u at [0..1023], v at [1024..2047], c-major ----
    if (lane < 32) {
        float* ex = uvx + role * 1024;
        #pragma unroll
        for (int cc = 0; cc < 2; ++cc) {
            *reinterpret_cast<float4*>(&ex[(2 * g + cc) * KDIM + 4 * kq]) =
                make_float4(a[cc][0], a[cc][1], a[cc][2], a[cc][3]);
        }
    }
    __syncthreads();   // B2: exchange visible

    // ---- dot: wave w owns c = C0+w; 64-lane butterfly -> stream 64 KB slab ----
    {
        const int c = C0 + w;
        const float2 uu = *reinterpret_cast<const float2*>(&uvx[w * KDIM + 2 * lane]);
        const float2 vv = *reinterpret_cast<const float2*>(&uvx[1024 + w * KDIM + 2 * lane]);
        const float br = b_row[c];     // wave-uniform -> s_load
        const float bc = b_col[c];
        float p = (uu.x + br) * (vv.x + bc) + (uu.y + br) * (vv.y + bc);
        #pragma unroll
        for (int off = 1; off < 64; off <<= 1) p += __shfl_xor(p, off);
        // p uniform across the wave -> stream slab c (64 KB), 1 KB/instr
        float4 v4;
        v4.x = v4.y = v4.z = v4.w = p;
        float4* o = reinterpret_cast<float4*>(out) + (size_t)(b * CDIM + c) * 4096;
        #pragma unroll 8
        for (int r = 0; r < 64; ++r) {
            o[lane + 64 * r] = v4;
        }
    }
}

extern "C" void kernel_launch(void* const* d_in, const int* in_sizes, int n_in,
                              void* d_out, int out_size, void* d_ws, size_t ws_size,
                              hipStream_t stream) {
    const float* x     = (const float*)d_in[0];
    const float* w_col = (const float*)d_in[1];
    const float* b_col = (const float*)d_in[2];
    const float* w_row = (const float*)d_in[3];
    const float* b_row = (const float*)d_in[4];
    float* out = (float*)d_out;

    fused_kernel<<<512, 512, 0, stream>>>(x, w_col, b_col, w_row, b_row, out);
}